// Round 8
// baseline (377.217 us; speedup 1.0000x reference)
//
#include <hip/hip_runtime.h>

// NGNNConv: out[i,j,:] = m[i,j] * [ (sum_{e: erow[e]=j} m[i,ecol[e]] * X[i,ecol[e],:]) @ W + b*cnt ]
// N=1024, E=8192, IND=OUTD=32, fp32.
//
// R6 design (resubmitted; four infra failures, never measured):
// half-wave-per-j COALESCED gathers.
//  - R5 post-mortem: thread-per-j gathers put 64 distinct cache lines under
//    every load instruction (random k per lane) and run every inner loop to
//    max(cn) over 64 lanes (~13 vs mean 4). 146 us with VALU 24%/HBM 19% =
//    transaction+divergence bound, not BW or conflicts.
//  - Now a 32-lane half-wave owns one j: each source row X[i,k,:] (128 B) is
//    read as 32 consecutive dwords -> ONE instruction, 2 lines (minimum).
//    Trip-count divergence is between 2 j's, not 64.
//  - 32x32 matmul: S redistributed via a per-wave 64-float LDS buffer
//    (broadcast ds_read_b128), W column in 32 regs/lane, 4 partial accums.
//  - Output row = 32 coalesced dwords per half-wave.
//  - CSR build fused into ONE single-block kernel (LDS count+scan+scatter):
//    2 dispatches total (was 5).

#define NN   1024
#define IND  32
#define OUTD 32
#define EE   8192

// ---------------- fused CSR builder: one block, one dispatch ----------------
__global__ __launch_bounds__(1024) void k_csr(const int* __restrict__ erow,
                                              const int* __restrict__ ecol,
                                              int* __restrict__ row_ptr,
                                              int* __restrict__ cols,
                                              int n_edges) {
    __shared__ int sb[NN];
    __shared__ int fill[NN];
    const int t = threadIdx.x;

    int er[8], ec[8];
    #pragma unroll
    for (int it = 0; it < 8; ++it) {
        const int e = it * 1024 + t;
        er[it] = (e < n_edges) ? (erow[e] & (NN - 1)) : -1;
        ec[it] = (e < n_edges) ? (ecol[e] & (NN - 1)) : 0;
    }
    sb[t] = 0;
    __syncthreads();
    #pragma unroll
    for (int it = 0; it < 8; ++it)
        if (er[it] >= 0) atomicAdd(&sb[er[it]], 1);
    __syncthreads();
    const int v = sb[t];
    for (int off = 1; off < NN; off <<= 1) {          // Hillis-Steele inclusive
        const int a = (t >= off) ? sb[t - off] : 0;
        __syncthreads();
        sb[t] += a;
        __syncthreads();
    }
    const int excl = sb[t] - v;
    row_ptr[t] = excl;
    fill[t]    = excl;
    if (t == NN - 1) row_ptr[NN] = sb[t];
    __syncthreads();
    #pragma unroll
    for (int it = 0; it < 8; ++it)
        if (er[it] >= 0) {
            const int pos = atomicAdd(&fill[er[it]], 1);
            cols[pos] = ec[it];
        }
}

// ---------------- main: block per i, 256 threads, half-wave per j ----------------
__global__ __launch_bounds__(256, 4) void ngnn_main_kernel(
    const float* __restrict__ X, const int* __restrict__ mask,
    const float* __restrict__ W, const float* __restrict__ b,
    const int* __restrict__ row_ptr, const int* __restrict__ cols,
    float* __restrict__ out)
{
    __shared__ float          maskf[NN];       // 4 KB
    __shared__ unsigned int   meta[NN];        // e0 | cn<<16 (active j only)
    __shared__ unsigned short colsl[EE];       // compacted active sources (16 KB)
    __shared__ unsigned short alist[NN];       // active-j worklist (2 KB)
    __shared__ float          Sbuf[4][64];     // per-wave S exchange (1 KB)
    __shared__ int            acount;

    const int t = threadIdx.x;
    const int i = blockIdx.x;
    const int l = t & 63;                      // lane
    const int w = t >> 6;                      // wave 0..3
    const int h = l >> 5;                      // half 0/1
    const int d = l & 31;                      // dim / out-channel lane role

    // W column + bias preload (lane d holds W[:,d]); hides under fold phase.
    float wl[IND];
    #pragma unroll
    for (int dd = 0; dd < IND; ++dd) wl[dd] = W[dd * OUTD + d];
    const float b_c = b[d];

    if (t == 0) acount = 0;
    {   // mask row -> LDS (coalesced int4)
        const int4 m4 = ((const int4*)(mask + (size_t)i * NN))[t];
        maskf[4*t+0] = (float)m4.x; maskf[4*t+1] = (float)m4.y;
        maskf[4*t+2] = (float)m4.z; maskf[4*t+3] = (float)m4.w;
    }
    __syncthreads();

    // ---- Fold: compact active sources per active j; build active-j list ----
    #pragma unroll
    for (int p = 0; p < 4; ++p) {
        const int j = p * 256 + t;
        if (maskf[j] != 0.f) {
            const int a   = row_ptr[j];
            const int bnd = row_ptr[j + 1];
            int c = 0;
            for (int e = a; e < bnd; ++e) {
                const int k = cols[e] & (NN - 1);
                if (maskf[k] != 0.f) colsl[a + (c++)] = (unsigned short)k;
            }
            meta[j] = (unsigned)a | ((unsigned)c << 16);
            const int pos = atomicAdd(&acount, 1);
            alist[pos] = (unsigned short)j;
        }
    }
    __syncthreads();

    // ---- Zero-store sweep for inactive j (fire-and-forget, coalesced rows) ----
    const float4 z = {0.f, 0.f, 0.f, 0.f};
    #pragma unroll
    for (int p = 0; p < 4; ++p) {
        const int j = p * 256 + t;
        if (maskf[j] == 0.f) {
            float4* orow = (float4*)(out + ((size_t)i * NN + j) * OUTD);
            #pragma unroll
            for (int q = 0; q < 8; ++q) orow[q] = z;
        }
    }

    // ---- Hot loop: one j per half-wave, coalesced 128 B row gathers ----
    const float* Xd = X + (size_t)i * NN * IND + d;   // lane's dim slice
    const int na = acount;

    for (int p = w; 2 * p < na; p += 4) {
        const int idx  = 2 * p + h;
        const int live = (idx < na) ? 1 : 0;
        const int j    = live ? (int)alist[idx] : 0;
        const unsigned md = live ? meta[j] : 0u;
        const int e0 = (int)(md & 0xffffu);
        const int cn = (int)(md >> 16);

        // Gather: row k read as 32 consecutive dwords by the half-wave.
        float S = 0.f;
        int q = 0;
        for (; q + 4 <= cn; q += 4) {                 // 4-deep MLP batch
            const int k0 = (int)colsl[e0 + q + 0];    // LDS broadcast reads
            const int k1 = (int)colsl[e0 + q + 1];
            const int k2 = (int)colsl[e0 + q + 2];
            const int k3 = (int)colsl[e0 + q + 3];
            const float v0 = Xd[(size_t)k0 << 5];
            const float v1 = Xd[(size_t)k1 << 5];
            const float v2 = Xd[(size_t)k2 << 5];
            const float v3 = Xd[(size_t)k3 << 5];
            S += (v0 + v1) + (v2 + v3);
        }
        for (; q < cn; ++q)
            S += Xd[(size_t)colsl[e0 + q] << 5];

        // Redistribute S across the half-wave via per-wave LDS buffer.
        Sbuf[w][l] = S;
        asm volatile("s_waitcnt lgkmcnt(0)" ::: "memory");  // same-wave ds order

        // o[c] = b[c]*cn + sum_d S[d] * W[d][c]; lane role: c = d.
        const float cf = (float)cn;
        const float4* Sb = (const float4*)&Sbuf[w][h << 5];
        float o0 = b_c * cf, o1 = 0.f, o2 = 0.f, o3 = 0.f;
        #pragma unroll
        for (int qq = 0; qq < 8; ++qq) {
            const float4 s4 = Sb[qq];                 // broadcast ds_read_b128
            o0 = fmaf(s4.x, wl[4*qq+0], o0);
            o1 = fmaf(s4.y, wl[4*qq+1], o1);
            o2 = fmaf(s4.z, wl[4*qq+2], o2);
            o3 = fmaf(s4.w, wl[4*qq+3], o3);
        }
        const float o = (o0 + o1) + (o2 + o3);

        if (live)                                     // coalesced 128 B row store
            out[((size_t)i * NN + j) * OUTD + d] = o;
    }
}

extern "C" void kernel_launch(void* const* d_in, const int* in_sizes, int n_in,
                              void* d_out, int out_size, void* d_ws, size_t ws_size,
                              hipStream_t stream) {
    const float* X    = (const float*)d_in[0];
    const int*   mask = (const int*)d_in[1];
    const int*   erow = (const int*)d_in[2];
    const int*   ecol = (const int*)d_in[3];
    const float* W    = (const float*)d_in[4];
    const float* b    = (const float*)d_in[5];
    float*       out  = (float*)d_out;

    int n_edges = in_sizes[2];
    if (n_edges > EE) n_edges = EE;   // capacity guard

    // ws layout (ints): row_ptr[1025] | cols @2048
    int* row_ptr = (int*)d_ws;
    int* cols    = row_ptr + 2048;

    k_csr<<<1, 1024, 0, stream>>>(erow, ecol, row_ptr, cols, n_edges);
    ngnn_main_kernel<<<NN, 256, 0, stream>>>(X, mask, W, b, row_ptr, cols, out);
}

// Round 12
// 357.774 us; speedup vs baseline: 1.0543x; 1.0543x over previous
//
#include <hip/hip_runtime.h>

// NGNNConv: out[i,j,:] = m[i,j] * [ (sum_{e: erow[e]=j} m[i,ecol[e]] * X[i,ecol[e],:]) @ W + b*cnt ]
// N=1024, E=8192, IND=OUTD=32, fp32.
//
// R7 design (resubmitted; three acquisition timeouts, never measured):
// R5 (best measured, 146 us) + occupancy fix. Single-variable change.
//  - R6 post-mortem: half-wave-per-j coalescing KILLED memory-level parallelism
//    (4 loads in flight, lgkmcnt(0) drain per iteration) -> 183 us. Reverted.
//  - R5 was GRID-capped: 1024 blocks = exactly 4 blocks/CU (occupancy 38%)
//    while its 27 KB LDS allowed 6. Latency-bound kernel + idle wave slots.
//  - Now each i is split into 2 j-half blocks: grid 2048, LDS ~23 KB,
//    __launch_bounds__(256,6) -> 6 blocks/CU resident (24 waves, 75%).
//    1.5x more loads in flight; per-block tail halves.
//  - CSR via the 4-kernel parallel chain (graph-captured => dispatches ~free;
//    R6's single-block k_csr scan measured ~10-20 us slower).

#define NN     1024
#define IND    32
#define OUTD   32
#define EE     8192
#define JSPLIT 2
#define JB     (NN / JSPLIT)   // 512 j's per block

typedef __attribute__((ext_vector_type(2))) float f32x2;

// ---------------- CSR build (parallel, 4 tiny kernels) ----------------
__global__ __launch_bounds__(1024) void k_zero(int* __restrict__ p, int n) {
    const int t = blockIdx.x * 1024 + threadIdx.x;
    if (t < n) p[t] = 0;
}

__global__ __launch_bounds__(1024) void k_count(const int* __restrict__ erow,
                                                int* __restrict__ cnt, int n_edges) {
    const int e = blockIdx.x * 1024 + threadIdx.x;
    if (e < n_edges) atomicAdd(&cnt[erow[e] & (NN - 1)], 1);
}

__global__ __launch_bounds__(1024) void k_scan(const int* __restrict__ cnt,
                                               int* __restrict__ row_ptr,
                                               int* __restrict__ fill) {
    __shared__ int sb[NN];
    const int t = threadIdx.x;
    const int v = cnt[t];
    sb[t] = v;
    __syncthreads();
    #pragma unroll
    for (int off = 1; off < NN; off <<= 1) {
        const int a = (t >= off) ? sb[t - off] : 0;
        __syncthreads();
        sb[t] += a;
        __syncthreads();
    }
    const int excl = sb[t] - v;
    row_ptr[t] = excl;
    fill[t]    = excl;
    if (t == NN - 1) row_ptr[NN] = sb[t];
}

__global__ __launch_bounds__(1024) void k_scatter(const int* __restrict__ erow,
                                                  const int* __restrict__ ecol,
                                                  int* __restrict__ fill,
                                                  int* __restrict__ cols, int n_edges) {
    const int e = blockIdx.x * 1024 + threadIdx.x;
    if (e < n_edges) {
        const int pos = atomicAdd(&fill[erow[e] & (NN - 1)], 1);
        cols[pos] = ecol[e];
    }
}

// ---------------- main: block per (i, j-half), 256 threads ----------------
__global__ __launch_bounds__(256, 6) void ngnn_main_kernel(
    const float* __restrict__ X, const int* __restrict__ mask,
    const float* __restrict__ W, const float* __restrict__ b,
    const int* __restrict__ row_ptr, const int* __restrict__ cols,
    float* __restrict__ out)
{
    __shared__ float          maskf[NN];       // 4 KB (all k needed for source mask)
    __shared__ unsigned int   meta[JB];        // 2 KB: e0_rel | cn<<16 (local j)
    __shared__ unsigned short colsl[EE];       // 16 KB compacted sources (rel offsets)
    __shared__ unsigned short alist[JB];       // 1 KB active local-j worklist
    __shared__ int            acount;

    const int t     = threadIdx.x;
    const int bid   = blockIdx.x;
    const int i     = bid >> 1;                // subgraph
    const int jbase = (bid & 1) * JB;          // j-half owned by this block

    if (t == 0) acount = 0;
    {   // full mask row -> LDS (coalesced int4: 256 threads x 4 = 1024)
        const int4 m4 = ((const int4*)(mask + (size_t)i * NN))[t];
        maskf[4*t+0] = (float)m4.x; maskf[4*t+1] = (float)m4.y;
        maskf[4*t+2] = (float)m4.z; maskf[4*t+3] = (float)m4.w;
    }
    __syncthreads();

    const int rbase = row_ptr[jbase];          // wave-uniform

    // ---- Fold: compact active sources per active j (2 j's per thread) ----
    #pragma unroll
    for (int p = 0; p < 2; ++p) {
        const int j = jbase + p * 256 + t;
        if (maskf[j] != 0.f) {
            const int a   = row_ptr[j];
            const int bnd = row_ptr[j + 1];
            const int ra  = a - rbase;         // relative slot in colsl (< EE always)
            int c = 0;
            for (int e = a; e < bnd; ++e) {
                const int k = cols[e] & (NN - 1);
                if (maskf[k] != 0.f) colsl[ra + (c++)] = (unsigned short)k;
            }
            meta[j - jbase] = (unsigned)ra | ((unsigned)c << 16);
            const int pos = atomicAdd(&acount, 1);
            alist[pos] = (unsigned short)(j - jbase);
        }
    }
    __syncthreads();

    // ---- Zero-store sweep for inactive j (fire-and-forget) ----
    const float4 z = {0.f, 0.f, 0.f, 0.f};
    #pragma unroll
    for (int p = 0; p < 2; ++p) {
        const int j = jbase + p * 256 + t;
        if (maskf[j] == 0.f) {
            float4* orow = (float4*)(out + ((size_t)i * NN + j) * OUTD);
            #pragma unroll
            for (int q = 0; q < 8; ++q) orow[q] = z;
        }
    }

    // ---- Process active j's (compacted -> full lanes on the hot path) ----
    const float4* Xi = (const float4*)(X + (size_t)i * NN * IND);
    const f32x2*  W2 = (const f32x2*)W;
    const f32x2*  b2 = (const f32x2*)b;
    const int na = acount;

    for (int a = t; a < na; a += 256) {
        const int j = jbase + (int)alist[a];
        const unsigned md = meta[(int)alist[a]];
        const int e0 = (int)(md & 0xffffu);
        const int cn = (int)(md >> 16);

        float4 S4[8];
        #pragma unroll
        for (int s = 0; s < 8; ++s) S4[s] = z;

        for (int q = 0; q < cn; ++q) {
            const int k = (int)colsl[e0 + q];
            const float4* r = Xi + (k << 3);        // 128 B contiguous row
            #pragma unroll
            for (int s = 0; s < 8; ++s) {           // 8 dwordx4, issued back-to-back
                const float4 v = r[s];
                S4[s].x += v.x; S4[s].y += v.y; S4[s].z += v.z; S4[s].w += v.w;
            }
        }

        // o = S @ W + b*cnt   (W/b wave-uniform -> scalar loads)
        const float cf = (float)cn;
        f32x2 o2[16];
        #pragma unroll
        for (int c = 0; c < 16; ++c) o2[c] = b2[c] * cf;
        #pragma unroll
        for (int d = 0; d < IND; ++d) {
            const float sd = ((const float*)S4)[d];  // static after unroll
            #pragma unroll
            for (int c = 0; c < 16; ++c) o2[c] += W2[d * 16 + c] * sd;
        }

        float4* orow = (float4*)(out + ((size_t)i * NN + j) * OUTD);
        #pragma unroll
        for (int q2 = 0; q2 < 8; ++q2)
            orow[q2] = make_float4(o2[2*q2].x, o2[2*q2].y, o2[2*q2+1].x, o2[2*q2+1].y);
    }
}

extern "C" void kernel_launch(void* const* d_in, const int* in_sizes, int n_in,
                              void* d_out, int out_size, void* d_ws, size_t ws_size,
                              hipStream_t stream) {
    const float* X    = (const float*)d_in[0];
    const int*   mask = (const int*)d_in[1];
    const int*   erow = (const int*)d_in[2];
    const int*   ecol = (const int*)d_in[3];
    const float* W    = (const float*)d_in[4];
    const float* b    = (const float*)d_in[5];
    float*       out  = (float*)d_out;

    int n_edges = in_sizes[2];
    if (n_edges > EE) n_edges = EE;   // colsl capacity guard

    // ws layout (ints): cnt[1024] | row_ptr[1025] @1024 | fill[1024] @2560 | cols @4096
    int* cnt     = (int*)d_ws;
    int* row_ptr = cnt + 1024;
    int* fill    = cnt + 2560;
    int* cols    = cnt + 4096;

    const int eb = (n_edges + 1023) / 1024;
    k_zero   <<<1, 1024, 0, stream>>>(cnt, NN);
    k_count  <<<eb, 1024, 0, stream>>>(erow, cnt, n_edges);
    k_scan   <<<1, 1024, 0, stream>>>(cnt, row_ptr, fill);
    k_scatter<<<eb, 1024, 0, stream>>>(erow, ecol, fill, cols, n_edges);

    ngnn_main_kernel<<<NN * JSPLIT, 256, 0, stream>>>(X, mask, W, b, row_ptr, cols, out);
}